// Round 1
// baseline (280.643 us; speedup 1.0000x reference)
//
#include <hip/hip_runtime.h>
#include <hip/hip_bf16.h>

// Problem constants (from reference)
#define B_SZ 2048
#define NB   2000
#define DB   30
#define KK   20
#define LL   40
#define PP   2

__device__ __forceinline__ float sigmoidf_fast(float z) {
    return 1.0f / (1.0f + __expf(-z));
}
__device__ __forceinline__ float eluf(float x) {
    return x > 0.0f ? x : (__expf(x) - 1.0f);
}

// Kernel 1: w_act [NB][LL], zero g_T [LL][B], out = beta broadcast [B][K]
__global__ __launch_bounds__(256) void prep_kern(
    const float* __restrict__ locs,   // [NB][DB]
    const float* __restrict__ mu,     // [LL][DB]
    const float* __restrict__ r,      // [LL]
    const float* __restrict__ beta,   // [KK]
    float* __restrict__ w_act,        // [NB][LL]
    float* __restrict__ g_T,          // [LL][B]
    float* __restrict__ out)          // [B][KK]
{
    int tid = blockIdx.x * 256 + threadIdx.x;
    if (tid < NB * LL) {
        int m = tid / LL;
        int l = tid - m * LL;
        float kappa = 0.0f;
        #pragma unroll
        for (int d = 0; d < DB; ++d) {
            float diff = locs[m * DB + d] - mu[l * DB + d];
            kappa += diff * diff;
        }
        w_act[tid] = sigmoidf_fast(r[l] - kappa);
    }
    if (tid < LL * B_SZ) g_T[tid] = 0.0f;
    if (tid < B_SZ * KK) out[tid] = beta[tid % KK];
}

// Kernel 2: g_T[l][b] = sum_m x[b][m] * w_act[m][l]
// grid = 32 b-tiles * 8 m-splits = 256 blocks, 256 threads
__global__ __launch_bounds__(256) void g_kern(
    const float* __restrict__ x,      // [B][NB]
    const float* __restrict__ w_act,  // [NB][LL]
    float* __restrict__ g_T)          // [LL][B]
{
    __shared__ float xs[64 * 127];    // 64 rows, stride 127 (odd -> conflict-free)
    __shared__ float ws[125 * LL];

    int bb = blockIdx.x & 31;   // b tile
    int mq = blockIdx.x >> 5;   // m split (0..7), 250 m each
    int tid = threadIdx.x;
    int i = tid & 63;           // local b
    int w = tid >> 6;           // wave id: handles l in [w*10, w*10+10)

    float acc[10];
    #pragma unroll
    for (int u = 0; u < 10; ++u) acc[u] = 0.0f;

    for (int c = 0; c < 2; ++c) {
        int m0 = mq * 250 + c * 125;
        __syncthreads();
        // stage x tile [64][125]
        for (int t = tid; t < 64 * 125; t += 256) {
            int ii = t / 125;
            int jj = t - ii * 125;
            xs[ii * 127 + jj] = x[(bb * 64 + ii) * NB + m0 + jj];
        }
        // stage w_act chunk [125][40] (contiguous)
        for (int t = tid; t < 125 * LL; t += 256) {
            ws[t] = w_act[m0 * LL + t];
        }
        __syncthreads();
        #pragma unroll 5
        for (int m = 0; m < 125; ++m) {
            float xv = xs[i * 127 + m];
            const float* wrow = &ws[m * LL + w * 10];
            #pragma unroll
            for (int u = 0; u < 10; ++u)
                acc[u] += xv * wrow[u];   // same address per wave -> LDS broadcast
        }
    }
    #pragma unroll
    for (int u = 0; u < 10; ++u) {
        atomicAdd(&g_T[(w * 10 + u) * B_SZ + bb * 64 + i], acc[u]);
    }
}

// Kernel 3: NAM MLPs + reduction.
// blockIdx.x = bb(8) + 8*( lc(4) + 4*( p(2) + 2*k(20) ) ) = 1280 blocks, 256 thr
// thread -> b = bb*256 + tid; loops over 10 l's; weight indices block-uniform.
__global__ __launch_bounds__(256) void nam_kern(
    const float* __restrict__ g_T,    // [LL][B]
    const float* __restrict__ alpha,  // [LL][KK]
    const float* __restrict__ W1,     // [K][L][P][16]
    const float* __restrict__ b1,     // [K][L][P][16]
    const float* __restrict__ W2,     // [K][L][P][16][16]
    const float* __restrict__ b2,     // [K][L][P][16]
    const float* __restrict__ W3,     // [K][L][P][16][8]
    const float* __restrict__ b3,     // [K][L][P][8]
    const float* __restrict__ W4,     // [K][L][P][8]
    const float* __restrict__ b4,     // [K][L][P]
    float* __restrict__ out)          // [B][KK]
{
    int bid = blockIdx.x;
    int bb = bid & 7;
    int lc = (bid >> 3) & 3;
    int p  = (bid >> 5) & 1;
    int k  = bid >> 6;
    int b  = bb * 256 + threadIdx.x;

    float gv[10];
    #pragma unroll
    for (int u = 0; u < 10; ++u)
        gv[u] = g_T[(lc * 10 + u) * B_SZ + b];   // coalesced

    float acc = 0.0f;

    #pragma unroll 1
    for (int u = 0; u < 10; ++u) {
        int l = lc * 10 + u;
        int base = (k * LL + l) * PP + p;   // uniform per block
        const float* w1 = W1 + base * 16;
        const float* c1 = b1 + base * 16;
        const float* w2 = W2 + base * 256;
        const float* c2 = b2 + base * 16;
        const float* w3 = W3 + base * 128;
        const float* c3 = b3 + base * 8;
        const float* w4 = W4 + base * 8;
        float        c4 = b4[base];

        float s = gv[u];

        float h1[16];
        #pragma unroll
        for (int i = 0; i < 16; ++i)
            h1[i] = eluf(s * w1[i] + c1[i]);

        float h2[16];
        #pragma unroll
        for (int j = 0; j < 16; ++j) h2[j] = c2[j];
        #pragma unroll
        for (int i = 0; i < 16; ++i) {
            float hv = h1[i];
            #pragma unroll
            for (int j = 0; j < 16; ++j)
                h2[j] += hv * w2[i * 16 + j];
        }
        #pragma unroll
        for (int j = 0; j < 16; ++j) h2[j] = eluf(h2[j]);

        float h3[8];
        #pragma unroll
        for (int j = 0; j < 8; ++j) h3[j] = c3[j];
        #pragma unroll
        for (int i = 0; i < 16; ++i) {
            float hv = h2[i];
            #pragma unroll
            for (int j = 0; j < 8; ++j)
                h3[j] += hv * w3[i * 8 + j];
        }

        float f = c4;
        #pragma unroll
        for (int j = 0; j < 8; ++j)
            f += eluf(h3[j]) * w4[j];

        float aact = sigmoidf_fast(alpha[l * KK + k]);
        acc += aact * f;
    }

    atomicAdd(&out[b * KK + k], acc);
}

extern "C" void kernel_launch(void* const* d_in, const int* in_sizes, int n_in,
                              void* d_out, int out_size, void* d_ws, size_t ws_size,
                              hipStream_t stream) {
    const float* x     = (const float*)d_in[0];
    const float* locs  = (const float*)d_in[1];
    const float* mu    = (const float*)d_in[2];
    const float* r     = (const float*)d_in[3];
    const float* alpha = (const float*)d_in[4];
    const float* beta  = (const float*)d_in[5];
    const float* W1    = (const float*)d_in[6];
    const float* b1    = (const float*)d_in[7];
    const float* W2    = (const float*)d_in[8];
    const float* b2    = (const float*)d_in[9];
    const float* W3    = (const float*)d_in[10];
    const float* b3    = (const float*)d_in[11];
    const float* W4    = (const float*)d_in[12];
    const float* b4    = (const float*)d_in[13];
    float* out = (float*)d_out;

    float* ws0   = (float*)d_ws;
    float* w_act = ws0;                 // NB*LL   = 80000 floats
    float* g_T   = ws0 + NB * LL;       // LL*B    = 81920 floats

    // prep: covers max(80000, 81920, 40960) -> 320 blocks
    prep_kern<<<320, 256, 0, stream>>>(locs, mu, r, beta, w_act, g_T, out);
    // g = x @ w_act (transposed output)
    g_kern<<<256, 256, 0, stream>>>(x, w_act, g_T);
    // NAM + reduce
    nam_kern<<<1280, 256, 0, stream>>>(g_T, alpha, W1, b1, W2, b2, W3, b3, W4, b4, out);
}

// Round 2
// 175.270 us; speedup vs baseline: 1.6012x; 1.6012x over previous
//
#include <hip/hip_runtime.h>
#include <hip/hip_bf16.h>

// Problem constants (from reference)
#define B_SZ 2048
#define NB   2000
#define DB   30
#define KK   20
#define LL   40
#define PP   2

// Repacked per-(k,l,p) blob layout (floats), stride 452 (16B-aligned):
//   0: W1[16] | 16: b1[16] | 32: b2[16] | 48: W2[256] | 304: W3[128]
// 432: b3[8] | 440: W4[8]*aact | 448: b4*aact | 449..451: pad
#define BLOB_STRIDE 452

__device__ __forceinline__ float sigmoidf_fast(float z) {
    return 1.0f / (1.0f + __expf(-z));
}
__device__ __forceinline__ float eluf(float x) {
    return x > 0.0f ? x : (__expf(x) - 1.0f);
}

// Kernel 1: w_act [NB][LL], zero g_T [LL][B], out = beta broadcast [B][K]
__global__ __launch_bounds__(256) void prep_kern(
    const float* __restrict__ locs,   // [NB][DB]
    const float* __restrict__ mu,     // [LL][DB]
    const float* __restrict__ r,      // [LL]
    const float* __restrict__ beta,   // [KK]
    float* __restrict__ w_act,        // [NB][LL]
    float* __restrict__ g_T,          // [LL][B]
    float* __restrict__ out)          // [B][KK]
{
    int tid = blockIdx.x * 256 + threadIdx.x;
    if (tid < NB * LL) {
        int m = tid / LL;
        int l = tid - m * LL;
        float kappa = 0.0f;
        #pragma unroll
        for (int d = 0; d < DB; ++d) {
            float diff = locs[m * DB + d] - mu[l * DB + d];
            kappa += diff * diff;
        }
        w_act[tid] = sigmoidf_fast(r[l] - kappa);
    }
    if (tid < LL * B_SZ) g_T[tid] = 0.0f;
    if (tid < B_SZ * KK) out[tid] = beta[tid % KK];
}

// Kernel 1b: repack weights into consumption-order blobs; fold sigmoid(alpha)
// into W4/b4. One 64-thread block per (k,l,p); idx = (k*LL+l)*PP+p.
__global__ __launch_bounds__(64) void repack_kern(
    const float* __restrict__ alpha,  // [LL][KK]
    const float* __restrict__ W1, const float* __restrict__ b1,
    const float* __restrict__ W2, const float* __restrict__ b2,
    const float* __restrict__ W3, const float* __restrict__ b3,
    const float* __restrict__ W4, const float* __restrict__ b4,
    float* __restrict__ blob)
{
    int idx = blockIdx.x;            // 0..1599
    int kl  = idx >> 1;              // k*LL + l
    int l   = kl % LL;
    int k   = kl / LL;
    int t   = threadIdx.x;           // 0..63
    float* o = blob + (size_t)idx * BLOB_STRIDE;

    if (t < 16) {
        o[t]      = W1[idx * 16 + t];
        o[16 + t] = b1[idx * 16 + t];
        o[32 + t] = b2[idx * 16 + t];
    }
    #pragma unroll
    for (int rr = 0; rr < 4; ++rr)
        o[48 + rr * 64 + t] = W2[idx * 256 + rr * 64 + t];
    #pragma unroll
    for (int rr = 0; rr < 2; ++rr)
        o[304 + rr * 64 + t] = W3[idx * 128 + rr * 64 + t];

    float aact = sigmoidf_fast(alpha[l * KK + k]);
    if (t < 8) {
        o[432 + t] = b3[idx * 8 + t];
        o[440 + t] = W4[idx * 8 + t] * aact;
    }
    if (t == 0) {
        o[448] = b4[idx] * aact;
        o[449] = 0.0f; o[450] = 0.0f; o[451] = 0.0f;
    }
}

// Kernel 2: g_T[l][b] += sum_m x[b][m] * w_act[m][l]
// grid = 32 b-tiles * 16 m-splits = 512 blocks, 256 threads
__global__ __launch_bounds__(256) void g_kern(
    const float* __restrict__ x,      // [B][NB]
    const float* __restrict__ w_act,  // [NB][LL]
    float* __restrict__ g_T)          // [LL][B]
{
    __shared__ float  xs[64 * 127];       // 64 rows, stride 127 (2-way alias only)
    __shared__ float4 ws4[1250];          // 125 m * 40 l

    int bb = blockIdx.x & 31;   // b tile (64 b each)
    int mq = blockIdx.x >> 5;   // m split (0..15), 125 m each
    int tid = threadIdx.x;
    int i = tid & 63;           // local b
    int w = tid >> 6;           // wave id: handles l in [w*10, w*10+10)

    // stage x tile [64][125]
    for (int t = tid; t < 64 * 125; t += 256) {
        int ii = t / 125;
        int jj = t - ii * 125;
        xs[ii * 127 + jj] = x[(bb * 64 + ii) * NB + mq * 125 + jj];
    }
    // stage w_act chunk [125][40] (contiguous, float4)
    {
        const float4* wa4 = (const float4*)w_act;
        for (int t = tid; t < 1250; t += 256)
            ws4[t] = wa4[mq * 1250 + t];
    }
    __syncthreads();

    const float* wsf = (const float*)ws4;
    float acc[10];
    #pragma unroll
    for (int u = 0; u < 10; ++u) acc[u] = 0.0f;

    #pragma unroll 5
    for (int m = 0; m < 125; ++m) {
        float xv = xs[i * 127 + m];
        const float* wrow = &wsf[m * LL + w * 10];
        #pragma unroll
        for (int u = 0; u < 10; ++u)
            acc[u] += xv * wrow[u];   // uniform addr per wave -> LDS broadcast
    }
    #pragma unroll
    for (int u = 0; u < 10; ++u)
        atomicAdd(&g_T[(w * 10 + u) * B_SZ + bb * 64 + i], acc[u]);
}

// Kernel 3: NAM MLPs + reduction, weights streamed from LDS (broadcast reads).
// bid = bb(4) | lc(4)<<2 | p(2)<<4 | k(20)<<5 -> 640 blocks, 256 threads,
// 2 b per thread (b0 = bb*512+tid, b1 = b0+256).
__global__ __launch_bounds__(256) void nam_kern(
    const float* __restrict__ g_T,    // [LL][B]
    const float* __restrict__ blob,   // [1600][BLOB_STRIDE]
    float* __restrict__ out)          // [B][KK]
{
    __shared__ __align__(16) float sw[10 * BLOB_STRIDE];

    int bid = blockIdx.x;
    int bb = bid & 3;
    int lc = (bid >> 2) & 3;
    int p  = (bid >> 4) & 1;
    int k  = bid >> 5;
    int tid = threadIdx.x;
    int b0 = bb * 512 + tid;
    int b1 = b0 + 256;

    // stage 10 blobs (18 KB) via float4
    {
        float4* sw4 = (float4*)sw;
        const float4* bl4 = (const float4*)blob;
        const int Q = BLOB_STRIDE / 4;          // 113
        for (int t = tid; t < 10 * Q; t += 256) {
            int u = t / Q;
            int rr = t - u * Q;
            int idx = (k * LL + lc * 10 + u) * PP + p;
            sw4[t] = bl4[(size_t)idx * Q + rr];
        }
    }
    __syncthreads();

    float acc0 = 0.0f, acc1 = 0.0f;

    #pragma unroll 1
    for (int u = 0; u < 10; ++u) {
        const float* W = &sw[u * BLOB_STRIDE];
        int l = lc * 10 + u;
        float s0 = g_T[l * B_SZ + b0];
        float s1 = g_T[l * B_SZ + b1];

        // layer 1: h1 = elu(s * W1 + b1)
        float h1a[16], h1b[16];
        {
            const float4* w1q = (const float4*)(W);
            const float4* c1q = (const float4*)(W + 16);
            #pragma unroll
            for (int q = 0; q < 4; ++q) {
                float4 wv = w1q[q], cv = c1q[q];
                h1a[q*4+0] = eluf(fmaf(s0, wv.x, cv.x));
                h1a[q*4+1] = eluf(fmaf(s0, wv.y, cv.y));
                h1a[q*4+2] = eluf(fmaf(s0, wv.z, cv.z));
                h1a[q*4+3] = eluf(fmaf(s0, wv.w, cv.w));
                h1b[q*4+0] = eluf(fmaf(s1, wv.x, cv.x));
                h1b[q*4+1] = eluf(fmaf(s1, wv.y, cv.y));
                h1b[q*4+2] = eluf(fmaf(s1, wv.z, cv.z));
                h1b[q*4+3] = eluf(fmaf(s1, wv.w, cv.w));
            }
        }

        // layer 2: h2 = elu(h1 @ W2 + b2)
        float h2a[16], h2b[16];
        {
            const float4* c2q = (const float4*)(W + 32);
            #pragma unroll
            for (int q = 0; q < 4; ++q) {
                float4 cv = c2q[q];
                h2a[q*4+0] = cv.x; h2a[q*4+1] = cv.y; h2a[q*4+2] = cv.z; h2a[q*4+3] = cv.w;
                h2b[q*4+0] = cv.x; h2b[q*4+1] = cv.y; h2b[q*4+2] = cv.z; h2b[q*4+3] = cv.w;
            }
            #pragma unroll
            for (int i = 0; i < 16; ++i) {
                float a0 = h1a[i], a1 = h1b[i];
                const float4* w2q = (const float4*)(W + 48 + i * 16);
                #pragma unroll
                for (int q = 0; q < 4; ++q) {
                    float4 wv = w2q[q];
                    h2a[q*4+0] = fmaf(a0, wv.x, h2a[q*4+0]);
                    h2a[q*4+1] = fmaf(a0, wv.y, h2a[q*4+1]);
                    h2a[q*4+2] = fmaf(a0, wv.z, h2a[q*4+2]);
                    h2a[q*4+3] = fmaf(a0, wv.w, h2a[q*4+3]);
                    h2b[q*4+0] = fmaf(a1, wv.x, h2b[q*4+0]);
                    h2b[q*4+1] = fmaf(a1, wv.y, h2b[q*4+1]);
                    h2b[q*4+2] = fmaf(a1, wv.z, h2b[q*4+2]);
                    h2b[q*4+3] = fmaf(a1, wv.w, h2b[q*4+3]);
                }
            }
            #pragma unroll
            for (int j = 0; j < 16; ++j) { h2a[j] = eluf(h2a[j]); h2b[j] = eluf(h2b[j]); }
        }

        // layer 3: h3 = h2 @ W3 + b3
        float h3a[8], h3b[8];
        {
            const float4* c3q = (const float4*)(W + 432);
            #pragma unroll
            for (int q = 0; q < 2; ++q) {
                float4 cv = c3q[q];
                h3a[q*4+0] = cv.x; h3a[q*4+1] = cv.y; h3a[q*4+2] = cv.z; h3a[q*4+3] = cv.w;
                h3b[q*4+0] = cv.x; h3b[q*4+1] = cv.y; h3b[q*4+2] = cv.z; h3b[q*4+3] = cv.w;
            }
            #pragma unroll
            for (int i = 0; i < 16; ++i) {
                float a0 = h2a[i], a1 = h2b[i];
                const float4* w3q = (const float4*)(W + 304 + i * 8);
                #pragma unroll
                for (int q = 0; q < 2; ++q) {
                    float4 wv = w3q[q];
                    h3a[q*4+0] = fmaf(a0, wv.x, h3a[q*4+0]);
                    h3a[q*4+1] = fmaf(a0, wv.y, h3a[q*4+1]);
                    h3a[q*4+2] = fmaf(a0, wv.z, h3a[q*4+2]);
                    h3a[q*4+3] = fmaf(a0, wv.w, h3a[q*4+3]);
                    h3b[q*4+0] = fmaf(a1, wv.x, h3b[q*4+0]);
                    h3b[q*4+1] = fmaf(a1, wv.y, h3b[q*4+1]);
                    h3b[q*4+2] = fmaf(a1, wv.z, h3b[q*4+2]);
                    h3b[q*4+3] = fmaf(a1, wv.w, h3b[q*4+3]);
                }
            }
        }

        // layer 4: f = elu(h3) . (W4*aact) + b4*aact  (aact pre-folded)
        {
            float f0 = W[448], f1 = W[448];
            const float4* w4q = (const float4*)(W + 440);
            #pragma unroll
            for (int q = 0; q < 2; ++q) {
                float4 wv = w4q[q];
                f0 = fmaf(eluf(h3a[q*4+0]), wv.x, f0);
                f0 = fmaf(eluf(h3a[q*4+1]), wv.y, f0);
                f0 = fmaf(eluf(h3a[q*4+2]), wv.z, f0);
                f0 = fmaf(eluf(h3a[q*4+3]), wv.w, f0);
                f1 = fmaf(eluf(h3b[q*4+0]), wv.x, f1);
                f1 = fmaf(eluf(h3b[q*4+1]), wv.y, f1);
                f1 = fmaf(eluf(h3b[q*4+2]), wv.z, f1);
                f1 = fmaf(eluf(h3b[q*4+3]), wv.w, f1);
            }
            acc0 += f0;
            acc1 += f1;
        }
    }

    atomicAdd(&out[b0 * KK + k], acc0);
    atomicAdd(&out[b1 * KK + k], acc1);
}

extern "C" void kernel_launch(void* const* d_in, const int* in_sizes, int n_in,
                              void* d_out, int out_size, void* d_ws, size_t ws_size,
                              hipStream_t stream) {
    const float* x     = (const float*)d_in[0];
    const float* locs  = (const float*)d_in[1];
    const float* mu    = (const float*)d_in[2];
    const float* r     = (const float*)d_in[3];
    const float* alpha = (const float*)d_in[4];
    const float* beta  = (const float*)d_in[5];
    const float* W1    = (const float*)d_in[6];
    const float* b1    = (const float*)d_in[7];
    const float* W2    = (const float*)d_in[8];
    const float* b2    = (const float*)d_in[9];
    const float* W3    = (const float*)d_in[10];
    const float* b3    = (const float*)d_in[11];
    const float* W4    = (const float*)d_in[12];
    const float* b4    = (const float*)d_in[13];
    float* out = (float*)d_out;

    float* ws0   = (float*)d_ws;
    float* w_act = ws0;                          // 80000 floats
    float* g_T   = ws0 + NB * LL;                // 81920 floats
    float* blob  = g_T + (size_t)LL * B_SZ;      // 1600*452 = 723200 floats

    prep_kern<<<320, 256, 0, stream>>>(locs, mu, r, beta, w_act, g_T, out);
    repack_kern<<<KK * LL * PP, 64, 0, stream>>>(alpha, W1, b1, W2, b2, W3, b3, W4, b4, blob);
    g_kern<<<512, 256, 0, stream>>>(x, w_act, g_T);
    nam_kern<<<640, 256, 0, stream>>>(g_T, blob, out);
}

// Round 3
// 157.999 us; speedup vs baseline: 1.7762x; 1.1093x over previous
//
#include <hip/hip_runtime.h>
#include <hip/hip_bf16.h>

// Problem constants
#define B_SZ 2048
#define NB   2000
#define DB   30
#define KK   20
#define LL   40
#define PP   2

typedef _Float16 f16x4 __attribute__((ext_vector_type(4)));
typedef float    f32x4 __attribute__((ext_vector_type(4)));

// Blob per (k,p,l) [stride 336 floats = 1344 B, 16B aligned], order [k][p][l]:
//   0: W1[16] f32 | 16: b1[16] f32 | 32: b2[16] f32
//  48: b3p[16] f32 (j'>=8 -> 0) | 64: W4f[16] f32 (W4*sigmoid(alpha), j'>=8 -> 0)
//  80: W2A 256 f16 in A-frag order | 208: W3A 256 f16 in A-frag order (rows j'>=8 zero)
#define BLOB_F 336

__device__ __forceinline__ float sigmoidf_fast(float z) {
    return 1.0f / (1.0f + __expf(-z));
}
__device__ __forceinline__ float eluf(float x) {
    return x > 0.0f ? x : (__expf(x) - 1.0f);
}

// beta_eff[k] = beta[k] + sum_{l,p} b4[k,l,p]*sigmoid(alpha[l,k])
__global__ __launch_bounds__(64) void beta_kern(
    const float* __restrict__ alpha, const float* __restrict__ beta,
    const float* __restrict__ b4, float* __restrict__ beta_eff)
{
    int k = threadIdx.x;
    if (k < KK) {
        float s = beta[k];
        for (int l = 0; l < LL; ++l) {
            float a = sigmoidf_fast(alpha[l * KK + k]);
            s += a * (b4[(k * LL + l) * PP + 0] + b4[(k * LL + l) * PP + 1]);
        }
        beta_eff[k] = s;
    }
}

// w_act[m][l] = sigmoid(r[l] - ||loc_m - mu_l||^2); out[b][k] = beta_eff[k]
__global__ __launch_bounds__(256) void prep_kern(
    const float* __restrict__ locs, const float* __restrict__ mu,
    const float* __restrict__ r, const float* __restrict__ beta_eff,
    float* __restrict__ w_act, float* __restrict__ out)
{
    __shared__ float smu[LL * DB];
    __shared__ float sr[LL];
    int tid = threadIdx.x;
    for (int t = tid; t < LL * DB; t += 256) smu[t] = mu[t];
    if (tid < LL) sr[tid] = r[tid];
    __syncthreads();

    int gid = blockIdx.x * 256 + tid;
    if (gid < NB * LL) {
        int m = gid / LL;
        int l = gid - m * LL;
        float kappa = 0.0f;
        #pragma unroll
        for (int d = 0; d < DB; ++d) {
            float diff = locs[m * DB + d] - smu[l * DB + d];
            kappa += diff * diff;
        }
        w_act[gid] = sigmoidf_fast(sr[l] - kappa);
    }
    if (gid < B_SZ * KK) out[gid] = beta_eff[gid % KK];
}

// Repack weights into MFMA A-fragment blobs (f16), fold sigmoid(alpha) into W4.
// One wave per (k,p,l): blockIdx = (k*2+p)*40 + l.
__global__ __launch_bounds__(64) void repack_kern(
    const float* __restrict__ alpha,
    const float* __restrict__ W1, const float* __restrict__ b1,
    const float* __restrict__ W2, const float* __restrict__ b2,
    const float* __restrict__ W3, const float* __restrict__ b3,
    const float* __restrict__ W4, float* __restrict__ blob)
{
    int bid = blockIdx.x;
    int k = bid / (PP * LL);
    int rem = bid - k * (PP * LL);
    int p = rem / LL;
    int l = rem - p * LL;
    int iw = (k * LL + l) * PP + p;     // original weight index
    int t = threadIdx.x;
    int n = t & 15, q = t >> 4;
    float* o = blob + (size_t)bid * BLOB_F;

    float aact = sigmoidf_fast(alpha[l * KK + k]);

    if (t < 16) {
        o[t]      = W1[iw * 16 + t];
        o[16 + t] = b1[iw * 16 + t];
        o[32 + t] = b2[iw * 16 + t];
        o[48 + t] = (t < 8) ? b3[iw * 8 + t] : 0.0f;
        o[64 + t] = (t < 8) ? W4[iw * 8 + t] * aact : 0.0f;
    }
    // W2A: a[j] = W2T[m=n][k=4q+j] = W2[(4q+j)*16 + n]
    _Float16* w2a = (_Float16*)(o + 80);
    #pragma unroll
    for (int j = 0; j < 4; ++j)
        w2a[t * 4 + j] = (_Float16)W2[iw * 256 + (4 * q + j) * 16 + n];
    // W3A: a[j] = (n<8) ? W3[(4q+j)*8 + n] : 0
    _Float16* w3a = (_Float16*)(o + 208);
    #pragma unroll
    for (int j = 0; j < 4; ++j)
        w3a[t * 4 + j] = (n < 8) ? (_Float16)W3[iw * 128 + (4 * q + j) * 8 + n]
                                 : (_Float16)0.0f;
}

// g partials: g_part[mq][l][b] = sum over m in split mq of x[b][m]*w_act[m][l]
// grid = 32 b-tiles * 8 m-splits = 256 blocks, 256 threads; no atomics.
__global__ __launch_bounds__(256) void g_kern(
    const float* __restrict__ x,      // [B][NB]
    const float* __restrict__ w_act,  // [NB][LL]
    float* __restrict__ g_part)       // [8][LL][B]
{
    __shared__ float  xs[64 * 127];
    __shared__ float4 ws4[1250];

    int bb = blockIdx.x & 31;
    int mq = blockIdx.x >> 5;          // 0..7, 250 m each
    int tid = threadIdx.x;
    int i = tid & 63;
    int w = tid >> 6;                  // l in [w*10, w*10+10)

    float acc[10];
    #pragma unroll
    for (int u = 0; u < 10; ++u) acc[u] = 0.0f;

    for (int c = 0; c < 2; ++c) {
        int m0 = mq * 250 + c * 125;
        __syncthreads();
        for (int t = tid; t < 64 * 125; t += 256) {
            int ii = t / 125;
            int jj = t - ii * 125;
            xs[ii * 127 + jj] = x[(bb * 64 + ii) * NB + m0 + jj];
        }
        {
            const float4* wa4 = (const float4*)w_act;
            for (int t = tid; t < 1250; t += 256)
                ws4[t] = wa4[m0 * 10 + t];   // m0*40/4 = m0*10
        }
        __syncthreads();
        const float* wsf = (const float*)ws4;
        #pragma unroll 5
        for (int m = 0; m < 125; ++m) {
            float xv = xs[i * 127 + m];
            const float* wrow = &wsf[m * LL + w * 10];
            #pragma unroll
            for (int u = 0; u < 10; ++u)
                acc[u] += xv * wrow[u];
        }
    }
    #pragma unroll
    for (int u = 0; u < 10; ++u)
        g_part[((size_t)mq * LL + w * 10 + u) * B_SZ + bb * 64 + i] = acc[u];
}

// g_T[l][b] = sum over 8 partials
__global__ __launch_bounds__(256) void g_reduce(
    const float* __restrict__ g_part, float* __restrict__ g_T)
{
    int t = blockIdx.x * 256 + threadIdx.x;   // 0..81919
    float s = 0.0f;
    #pragma unroll
    for (int mq = 0; mq < 8; ++mq)
        s += g_part[(size_t)mq * LL * B_SZ + t];
    g_T[t] = s;
}

// NAM via chained MFMA: hidden states feature-major [j][b]; C/D layout of one
// MFMA == B-operand layout of the next (col=lane&15=b, row/k=4*quad+reg=j).
// bid = bb(16) | lc(4)<<4 | p(2)<<6 | k(20)<<7 -> 2560 blocks, 256 threads.
// Wave handles 2 b-groups of 16; block covers 128 consecutive b.
__global__ __launch_bounds__(256) void nam_kern(
    const float* __restrict__ g_T,    // [LL][B]
    const float* __restrict__ blob,   // [K][P][LL][BLOB_F]
    float* __restrict__ out)          // [B][KK]
{
    __shared__ __align__(16) float sw[10 * BLOB_F];

    int bid = blockIdx.x;
    int bb = bid & 15;
    int lc = (bid >> 4) & 3;
    int p  = (bid >> 6) & 1;
    int k  = bid >> 7;
    int tid = threadIdx.x;

    // stage 10 blobs (13440 B)
    {
        const float4* bl4 = (const float4*)blob;
        float4* sw4 = (float4*)sw;
        size_t base = ((size_t)(k * PP + p) * LL + lc * 10) * (BLOB_F / 4);
        for (int t = tid; t < 10 * (BLOB_F / 4); t += 256)
            sw4[t] = bl4[base + t];
    }
    __syncthreads();

    int wv = tid >> 6;
    int lane = tid & 63;
    int n = lane & 15;
    int q = lane >> 4;
    int b0 = bb * 128 + wv * 32 + n;   // group 0; group 1 = b0+16

    float acc0 = 0.0f, acc1 = 0.0f;
    const f32x4 zero = {0.0f, 0.0f, 0.0f, 0.0f};

    #pragma unroll 1
    for (int u = 0; u < 10; ++u) {
        const float* W = sw + u * BLOB_F;
        f32x4 w1q = *(const f32x4*)(W + q * 4);
        f32x4 b1q = *(const f32x4*)(W + 16 + q * 4);
        f32x4 b2q = *(const f32x4*)(W + 32 + q * 4);
        f32x4 b3q = *(const f32x4*)(W + 48 + q * 4);
        f32x4 w4q = *(const f32x4*)(W + 64 + q * 4);
        f16x4 w2a = *(const f16x4*)((const _Float16*)(W + 80) + lane * 4);
        f16x4 w3a = *(const f16x4*)((const _Float16*)(W + 208) + lane * 4);

        int l = lc * 10 + u;
        float g0 = g_T[l * B_SZ + b0];
        float g1 = g_T[l * B_SZ + b0 + 16];

        // layer 1 (f32) -> f16 B-frag: b[j] = h1[i=4q+j][b=n]
        f16x4 hb0, hb1;
        #pragma unroll
        for (int j = 0; j < 4; ++j) {
            hb0[j] = (_Float16)eluf(fmaf(g0, w1q[j], b1q[j]));
            hb1[j] = (_Float16)eluf(fmaf(g1, w1q[j], b1q[j]));
        }

        // layer 2: D2[j][b] = W2T @ H1
        f32x4 d20 = __builtin_amdgcn_mfma_f32_16x16x16f16(w2a, hb0, zero, 0, 0, 0);
        f32x4 d21 = __builtin_amdgcn_mfma_f32_16x16x16f16(w2a, hb1, zero, 0, 0, 0);

        f16x4 hc0, hc1;
        #pragma unroll
        for (int j = 0; j < 4; ++j) {
            hc0[j] = (_Float16)eluf(d20[j] + b2q[j]);
            hc1[j] = (_Float16)eluf(d21[j] + b2q[j]);
        }

        // layer 3: D3[j'][b] = W3T @ H2 (rows j'>=8 are zero)
        f32x4 d30 = __builtin_amdgcn_mfma_f32_16x16x16f16(w3a, hc0, zero, 0, 0, 0);
        f32x4 d31 = __builtin_amdgcn_mfma_f32_16x16x16f16(w3a, hc1, zero, 0, 0, 0);

        // layer 4: acc += sum_r elu(h3[4q+r][b] + b3) * W4f[4q+r]
        // q>=2: d3=0, b3q=0 -> elu(0)=0, w4q=0 -> contributes 0.
        #pragma unroll
        for (int r = 0; r < 4; ++r) {
            acc0 = fmaf(eluf(d30[r] + b3q[r]), w4q[r], acc0);
            acc1 = fmaf(eluf(d31[r] + b3q[r]), w4q[r], acc1);
        }
    }

    // reduce across quads (lanes n, n+16, n+32, n+48 hold partials of batch b0)
    acc0 += __shfl_xor(acc0, 16, 64);
    acc0 += __shfl_xor(acc0, 32, 64);
    acc1 += __shfl_xor(acc1, 16, 64);
    acc1 += __shfl_xor(acc1, 32, 64);
    if (lane < 16) {
        atomicAdd(&out[(size_t)b0 * KK + k], acc0);
        atomicAdd(&out[(size_t)(b0 + 16) * KK + k], acc1);
    }
}

extern "C" void kernel_launch(void* const* d_in, const int* in_sizes, int n_in,
                              void* d_out, int out_size, void* d_ws, size_t ws_size,
                              hipStream_t stream) {
    const float* x     = (const float*)d_in[0];
    const float* locs  = (const float*)d_in[1];
    const float* mu    = (const float*)d_in[2];
    const float* r     = (const float*)d_in[3];
    const float* alpha = (const float*)d_in[4];
    const float* beta  = (const float*)d_in[5];
    const float* W1    = (const float*)d_in[6];
    const float* b1    = (const float*)d_in[7];
    const float* W2    = (const float*)d_in[8];
    const float* b2    = (const float*)d_in[9];
    const float* W3    = (const float*)d_in[10];
    const float* b3    = (const float*)d_in[11];
    const float* W4    = (const float*)d_in[12];
    const float* b4    = (const float*)d_in[13];
    float* out = (float*)d_out;

    float* ws0      = (float*)d_ws;
    float* w_act    = ws0;                                  //  80000
    float* g_T      = w_act + NB * LL;                      //  81920
    float* g_part   = g_T + LL * B_SZ;                      // 655360
    float* blob     = g_part + (size_t)8 * LL * B_SZ;       // 537600
    float* beta_eff = blob + (size_t)KK * PP * LL * BLOB_F; //     20

    beta_kern<<<1, 64, 0, stream>>>(alpha, beta, b4, beta_eff);
    prep_kern<<<320, 256, 0, stream>>>(locs, mu, r, beta_eff, w_act, out);
    repack_kern<<<KK * PP * LL, 64, 0, stream>>>(alpha, W1, b1, W2, b2, W3, b3, W4, blob);
    g_kern<<<256, 256, 0, stream>>>(x, w_act, g_part);
    g_reduce<<<320, 256, 0, stream>>>(g_part, g_T);
    nam_kern<<<2560, 256, 0, stream>>>(g_T, blob, out);
}